// Round 1
// baseline (112.026 us; speedup 1.0000x reference)
//
#include <hip/hip_runtime.h>

#define R 128
#define C 80
#define HH 28
#define WW 28
#define NPIX 784          // 28*28
#define NQ 196            // NPIX/4 (float4 chunks)
#define BIGD (1 << 26)    // sentinel for "no opposite pixel in this row"

// Fused single-kernel Hausdorff-DT loss, zero workspace.
//
// Identity used:  sum_i err[i,p]*cum[i,p] = sum_k dist[k,p] * sum_{i>=k} err[i,p]
// so block pair (k, parity) builds dist[k,.] = fieldP^2 + fieldT^2 in LDS
// (both blocks duplicate the cheap EDT), then each block dots it against the
// recomputed err of its parity-half of the suffix i >= k. Inputs for the err
// recompute (selected pred channels + targets, ~800 KB) are L2-resident.
// One float atomicAdd per block into out[0] (zeroed by a 4-B memset node).
__global__ __launch_bounds__(256) void hd_loss_fused(
    const float* __restrict__ preds,
    const float* __restrict__ targets,
    const int* __restrict__ labels,
    float* __restrict__ out)
{
    __shared__ unsigned fgrow[HH];        // fg mask bits per row (28 bits)
    __shared__ int rowd[2][HH][WW];       // min sq horiz dist to class-c pixel in row r, col x
    __shared__ int md2[NPIX];             // per-pixel min sq dist to opposite class
    __shared__ float dsum[NPIX];          // dist[k,p] = fieldP^2 + fieldT^2
    __shared__ int redF[256], redB[256];  // max-reduce scratch
    __shared__ float s_invF, s_invB;
    __shared__ int s_uni;
    __shared__ float wred[4];

    const int tid = threadIdx.x;
    const int bk = blockIdx.x;
    const int k = bk >> 1;                // image index this block owns
    const int par = bk & 1;               // which parity of the suffix it dots

    const int labk = labels[k];
    const float* __restrict__ pk = preds + ((size_t)k * C + (size_t)labk) * NPIX;
    const float* __restrict__ tk = targets + (size_t)k * NPIX;

    for (int j = tid; j < NPIX; j += 256) dsum[j] = 0.0f;  // same-thread accum below

    // ---- Phase 1: dist[k,.] = normalized field^2 of pred image + target image ----
    for (int f = 0; f < 2; ++f) {
        const float* __restrict__ src = f ? tk : pk;
        if (tid < HH) fgrow[tid] = 0u;
        __syncthreads();
        for (int j = tid; j < NPIX; j += 256) {
            const float v = src[j];
            const float s = f ? v : 1.0f / (1.0f + expf(-v));  // sigmoid for preds
            if (s > 0.5f) atomicOr(&fgrow[j / WW], 1u << (j % WW));
        }
        __syncthreads();

        // rowd[c][r][x]: min over cols kx with class(r,kx)==c of (x-kx)^2, via clz/ctz.
        for (int e = tid; e < 2 * NPIX; e += 256) {
            const int c = (e >= NPIX);
            const int rem = e - c * NPIX;
            const int r = rem / WW;
            const int x = rem - r * WW;
            const unsigned fr = fgrow[r];
            const unsigned w = c ? fr : (~fr & 0x0FFFFFFFu);
            int dv;
            if (w == 0u) {
                dv = BIGD;
            } else {
                const unsigned wl = w & ((2u << x) - 1u);  // bits 0..x
                const unsigned wr = w >> x;                // bits x..27
                const int dl = wl ? (x - (31 - __builtin_clz(wl))) : 10000;
                const int dr = wr ? __builtin_ctz(wr) : 10000;
                const int d = dl < dr ? dl : dr;
                dv = d * d;
            }
            rowd[c][r][x] = dv;
        }
        __syncthreads();

        // md2[p] = min over rows of dy^2 + rowd[opposite][r][x]; track per-class max.
        int localF = -1, localB = -1;
        for (int j = tid; j < NPIX; j += 256) {
            const int y = j / WW;
            const int x = j - y * WW;
            const int c = (fgrow[y] >> x) & 1;
            const int* rd = &rowd[c ^ 1][0][x];
            int m = 0x3FFFFFFF;
            #pragma unroll
            for (int r = 0; r < HH; ++r) {
                const int dy = y - r;
                const int cand = dy * dy + rd[r * WW];
                m = cand < m ? cand : m;
            }
            md2[j] = m;
            if (c) localF = m > localF ? m : localF;
            else   localB = m > localB ? m : localB;
        }
        redF[tid] = localF;
        redB[tid] = localB;
        __syncthreads();
        for (int s = 128; s > 0; s >>= 1) {
            if (tid < s) {
                redF[tid] = redF[tid + s] > redF[tid] ? redF[tid + s] : redF[tid];
                redB[tid] = redB[tid + s] > redB[tid] ? redB[tid + s] : redB[tid];
            }
            __syncthreads();
        }
        if (tid == 0) {
            const int mF = redF[0], mB = redB[0];
            if (mF < 0 || mB < 0) {   // uniform mask: field identically 0
                s_uni = 1; s_invF = 0.0f; s_invB = 0.0f;
            } else {
                s_uni = 0;
                s_invF = 1.0f / (float)mF;   // field^2 = md2 / max_md2(same class)
                s_invB = 1.0f / (float)mB;
            }
        }
        __syncthreads();
        if (!s_uni) {
            for (int j = tid; j < NPIX; j += 256) {
                const int y = j / WW;
                const int x = j - y * WW;
                const int c = (fgrow[y] >> x) & 1;
                dsum[j] += (float)md2[j] * (c ? s_invF : s_invB);
            }
        }
        __syncthreads();   // dsum done for this field; fgrow/md2 free for next f
    }

    // ---- Phase 2: acc = sum_{i>=k, i%2==par} sum_p err[i,p] * dsum[p] ----
    float acc = 0.0f;
    if (tid < NQ) {
        const float d0 = dsum[4 * tid + 0];
        const float d1 = dsum[4 * tid + 1];
        const float d2 = dsum[4 * tid + 2];
        const float d3 = dsum[4 * tid + 3];
        int i = ((k & 1) == par) ? k : k + 1;
        if (i < R) {
            float4 pv = ((const float4*)(preds + ((size_t)i * C + (size_t)labels[i]) * NPIX))[tid];
            float4 tv = ((const float4*)(targets + (size_t)i * NPIX))[tid];
            while (true) {
                const int inext = i + 2;
                float4 pn, tn;
                if (inext < R) {   // rotating 1-deep prefetch hides L2 latency
                    pn = ((const float4*)(preds + ((size_t)inext * C + (size_t)labels[inext]) * NPIX))[tid];
                    tn = ((const float4*)(targets + (size_t)inext * NPIX))[tid];
                }
                float e;
                e = 1.0f / (1.0f + expf(-pv.x)) - tv.x; acc += e * e * d0;
                e = 1.0f / (1.0f + expf(-pv.y)) - tv.y; acc += e * e * d1;
                e = 1.0f / (1.0f + expf(-pv.z)) - tv.z; acc += e * e * d2;
                e = 1.0f / (1.0f + expf(-pv.w)) - tv.w; acc += e * e * d3;
                if (inext >= R) break;
                pv = pn; tv = tn; i = inext;
            }
        }
    }

    // block reduce -> one atomicAdd per block
    #pragma unroll
    for (int off = 32; off > 0; off >>= 1)
        acc += __shfl_down(acc, off, 64);
    if ((tid & 63) == 0) wred[tid >> 6] = acc;
    __syncthreads();
    if (tid == 0)
        atomicAdd(out, (wred[0] + wred[1] + wred[2] + wred[3]) *
                           (1.0f / ((float)R * (float)NPIX)));
}

extern "C" void kernel_launch(void* const* d_in, const int* in_sizes, int n_in,
                              void* d_out, int out_size, void* d_ws, size_t ws_size,
                              hipStream_t stream) {
    const float* preds = (const float*)d_in[0];
    const float* targets = (const float*)d_in[1];
    const int* labels = (const int*)d_in[2];
    float* out = (float*)d_out;
    (void)d_ws; (void)ws_size; (void)in_sizes; (void)n_in; (void)out_size;

    hipMemsetAsync(out, 0, sizeof(float), stream);
    hipLaunchKernelGGL(hd_loss_fused, dim3(2 * R), dim3(256), 0, stream,
                       preds, targets, labels, out);
}